// Round 2
// baseline (1002.902 us; speedup 1.0000x reference)
//
#include <hip/hip_runtime.h>
#include <stdint.h>

// SparseLayer = dense GEMM: C[o][b] = sum_i W[i][o] * X[i][b]
//   M = OUT_F = 4096, N = BATCH = 8192, K = IN_F = 4096, fp32 in/out.
// Strategy: fp32 -> bf16 hi/lo split, 3-pass MFMA (hh + hl + lh), fp32 acc.
// Round 1: fixed compile error in convT, alignas(16) on LDS tiles.

#define IN_F 4096
#define OUT_F 4096
#define BATCH 8192

#define BM 128
#define BN 128
#define BK 64

typedef __bf16 bf16;
typedef __bf16 bf16x8 __attribute__((ext_vector_type(8)));
typedef float f32x4 __attribute__((ext_vector_type(4)));

// ---------------------------------------------------------------------------
// Transpose + split: in is R x C fp32 row-major.
// hi[c][r] + lo[c][r] ~= in[r][c]  (bf16 hi/lo split, ~2^-18 rel error)
// ---------------------------------------------------------------------------
__global__ __launch_bounds__(256) void convT_kernel(
    const float* __restrict__ in, bf16* __restrict__ hi, bf16* __restrict__ lo,
    int R, int C) {
  __shared__ float tile[64][65];  // +1 pad: conflict-free transpose
  const int r0 = blockIdx.y * 64;
  const int c0 = blockIdx.x * 64;
  const int tx = threadIdx.x;  // 0..31
  const int ty = threadIdx.y;  // 0..7
#pragma unroll
  for (int j = ty; j < 64; j += 8) {
    const float2 v = *reinterpret_cast<const float2*>(
        &in[(size_t)(r0 + j) * C + c0 + tx * 2]);
    tile[j][tx * 2] = v.x;
    tile[j][tx * 2 + 1] = v.y;
  }
  __syncthreads();
#pragma unroll
  for (int j = ty; j < 64; j += 8) {
    const float v0 = tile[tx * 2][j];
    const float v1 = tile[tx * 2 + 1][j];
    const bf16 h0 = (bf16)v0;
    const bf16 h1 = (bf16)v1;
    const bf16 g0 = (bf16)(v0 - (float)h0);
    const bf16 g1 = (bf16)(v1 - (float)h1);
    const size_t off = (size_t)(c0 + j) * R + (r0 + tx * 2);
    union { bf16 b[2]; unsigned u; } ph, pl;
    ph.b[0] = h0; ph.b[1] = h1;
    pl.b[0] = g0; pl.b[1] = g1;
    *reinterpret_cast<unsigned*>(&hi[off]) = ph.u;  // coalesced 4B stores
    *reinterpret_cast<unsigned*>(&lo[off]) = pl.u;
  }
}

// ---------------------------------------------------------------------------
// 3-pass bf16 GEMM.  A = [M][K] (W^T hi/lo), B = [N][K] (X^T hi/lo).
// acc += Ah*Bh + Ah*Bl + Al*Bh   (Al*Bl term ~2^-18, dropped)
// LDS: linear [row][64] bf16 tiles (128B rows); 16B chunk index XOR-swizzled
// by (row&7) on BOTH the global source (staging) and the ds_read (rule 21).
// ---------------------------------------------------------------------------
__device__ __forceinline__ void gload16(const bf16* g, bf16* l) {
  __builtin_amdgcn_global_load_lds(
      (const __attribute__((address_space(1))) void*)(g),
      (__attribute__((address_space(3))) void*)(l), 16, 0, 0);
}

__global__ __launch_bounds__(256, 2) void gemm3pass(
    const bf16* __restrict__ Ah, const bf16* __restrict__ Al,
    const bf16* __restrict__ Bh, const bf16* __restrict__ Bl,
    float* __restrict__ C) {
  __shared__ __align__(16) bf16 sAh[BM * BK], sAl[BM * BK];
  __shared__ __align__(16) bf16 sBh[BN * BK], sBl[BN * BK];

  const int tid = threadIdx.x;
  const int l = tid & 63;
  const int wid = tid >> 6;

  // XCD-aware swizzle: grid = 32*64 = 2048, divisible by 8.
  const int nwg = gridDim.x;
  const int cpx = nwg >> 3;
  const int bid = blockIdx.x;
  const int swz = (bid & 7) * cpx + (bid >> 3);
  const int nbn = BATCH / BN;  // 64
  const int mb = swz / nbn;
  const int nb = swz % nbn;

  // ---- staging geometry (constant across K loop) ----
  // One global_load_lds issue: 256 thr x 16B = 32 rows of 128B.
  // HW writes LDS linearly (wave base + lane*16); we pre-swizzle the SOURCE.
  const int srow = tid >> 3;                   // row within 32-row group
  const int schunk = (tid & 7) ^ (srow & 7);   // swizzled 16B chunk
  size_t offA[4], offB[4];
#pragma unroll
  for (int it = 0; it < 4; ++it) {
    const int r = it * 32 + srow;
    offA[it] = (size_t)(mb * BM + r) * IN_F + schunk * 8;
    offB[it] = (size_t)(nb * BN + r) * IN_F + schunk * 8;
  }
  const int ldsw = wid * 512;  // wave-uniform LDS base within 32-row group

  f32x4 acc[4][4];
#pragma unroll
  for (int i = 0; i < 4; ++i)
#pragma unroll
    for (int j = 0; j < 4; ++j)
      acc[i][j] = (f32x4){0.f, 0.f, 0.f, 0.f};

  // wave -> 64x64 output quadrant (2x2 wave grid)
  const int wm = (wid >> 1) * 64;
  const int wn = (wid & 1) * 64;
  const int rA = l & 15;
  const int g4 = l >> 4;

  for (int kt = 0; kt < IN_F; kt += BK) {
#pragma unroll
    for (int it = 0; it < 4; ++it) {
      const int lb = it * 2048 + ldsw;
      gload16(Ah + offA[it] + kt, sAh + lb);
      gload16(Al + offA[it] + kt, sAl + lb);
      gload16(Bh + offB[it] + kt, sBh + lb);
      gload16(Bl + offB[it] + kt, sBl + lb);
    }
    __syncthreads();  // compiler drains vmcnt before s_barrier -> tiles resident

#pragma unroll
    for (int ks = 0; ks < 2; ++ks) {
      bf16x8 ah[4], al[4], bh[4], bl[4];
      const int cb = ks * 4 + g4;  // logical 16B chunk (k-subtile)
#pragma unroll
      for (int i = 0; i < 4; ++i) {
        const int ra = wm + i * 16 + rA;
        const int oa = ra * 64 + ((cb ^ (ra & 7)) << 3);
        ah[i] = *reinterpret_cast<const bf16x8*>(sAh + oa);
        al[i] = *reinterpret_cast<const bf16x8*>(sAl + oa);
        const int rb = wn + i * 16 + rA;
        const int ob = rb * 64 + ((cb ^ (rb & 7)) << 3);
        bh[i] = *reinterpret_cast<const bf16x8*>(sBh + ob);
        bl[i] = *reinterpret_cast<const bf16x8*>(sBl + ob);
      }
#pragma unroll
      for (int i = 0; i < 4; ++i)
#pragma unroll
        for (int j = 0; j < 4; ++j) {
          acc[i][j] = __builtin_amdgcn_mfma_f32_16x16x32_bf16(ah[i], bh[j],
                                                              acc[i][j], 0, 0, 0);
          acc[i][j] = __builtin_amdgcn_mfma_f32_16x16x32_bf16(ah[i], bl[j],
                                                              acc[i][j], 0, 0, 0);
          acc[i][j] = __builtin_amdgcn_mfma_f32_16x16x32_bf16(al[i], bh[j],
                                                              acc[i][j], 0, 0, 0);
        }
    }
    __syncthreads();  // protect LDS before next stage
  }

  // Epilogue. 16x16x32 C/D layout: col = lane&15, row = (lane>>4)*4 + reg.
  const int m0 = mb * BM + wm + g4 * 4;
  const int n0 = nb * BN + wn + rA;
#pragma unroll
  for (int i = 0; i < 4; ++i)
#pragma unroll
    for (int j = 0; j < 4; ++j)
#pragma unroll
      for (int r = 0; r < 4; ++r)
        C[(size_t)(m0 + i * 16 + r) * BATCH + (n0 + j * 16)] = acc[i][j][r];
}

// ---------------------------------------------------------------------------
// Fallback (only if ws_size is too small): naive fp32, slow but correct.
// ---------------------------------------------------------------------------
__global__ __launch_bounds__(256) void naive_kernel(
    const float* __restrict__ W, const float* __restrict__ X,
    float* __restrict__ out) {
  const int n = blockIdx.x * 64 + threadIdx.x;
  const int m = blockIdx.y * 4 + threadIdx.y;
  float s = 0.f;
  for (int k = 0; k < IN_F; ++k)
    s = fmaf(W[(size_t)k * OUT_F + m], X[(size_t)k * BATCH + n], s);
  out[(size_t)m * BATCH + n] = s;
}

extern "C" void kernel_launch(void* const* d_in, const int* in_sizes, int n_in,
                              void* d_out, int out_size, void* d_ws,
                              size_t ws_size, hipStream_t stream) {
  const float* X = (const float*)d_in[0];  // (IN_F, BATCH)
  const float* W = (const float*)d_in[1];  // (IN_F, OUT_F)
  float* out = (float*)d_out;              // (OUT_F, BATCH)

  const size_t szA = (size_t)OUT_F * IN_F;
  const size_t szB = (size_t)BATCH * IN_F;
  const size_t need = (2 * szA + 2 * szB) * sizeof(bf16);  // 192 MB

  if (d_ws == nullptr || ws_size < need) {
    naive_kernel<<<dim3(BATCH / 64, OUT_F / 4), dim3(64, 4), 0, stream>>>(W, X,
                                                                          out);
    return;
  }

  bf16* Ah = (bf16*)d_ws;
  bf16* Al = Ah + szA;
  bf16* Bh = Al + szA;
  bf16* Bl = Bh + szB;

  // W (IN_F x OUT_F) -> Ah/Al (OUT_F x IN_F)
  convT_kernel<<<dim3(OUT_F / 64, IN_F / 64), dim3(32, 8), 0, stream>>>(
      W, Ah, Al, IN_F, OUT_F);
  // X (IN_F x BATCH) -> Bh/Bl (BATCH x IN_F)
  convT_kernel<<<dim3(BATCH / 64, IN_F / 64), dim3(32, 8), 0, stream>>>(
      X, Bh, Bl, IN_F, BATCH);

  gemm3pass<<<dim3((OUT_F / BM) * (BATCH / BN)), dim3(256), 0, stream>>>(
      Ah, Al, Bh, Bl, out);
}

// Round 3
// 989.589 us; speedup vs baseline: 1.0135x; 1.0135x over previous
//
#include <hip/hip_runtime.h>
#include <stdint.h>

// SparseLayer = dense GEMM: C[o][b] = sum_i W[i][o] * X[i][b]
//   M = OUT_F = 4096, N = BATCH = 8192, K = IN_F = 4096, fp32 in/out.
// fp32 -> bf16 hi/lo split, 3-pass MFMA (hh + hl + lh), fp32 acc.
// Round 3: 256x256xBK32 tile, 8 waves, double-buffered LDS with
// issue-early/wait-late staging (T3 minimum-2-phase), setprio (T5),
// chunk^((row>>1)&3) both-sides swizzle; fast vectorized transpose-convert.

#define IN_F 4096
#define OUT_F 4096
#define BATCH 8192

#define BM 256
#define BN 256
#define BK 32

typedef __bf16 bf16;
typedef __bf16 bf16x8 __attribute__((ext_vector_type(8)));
typedef float f32x4 __attribute__((ext_vector_type(4)));

// ---------------------------------------------------------------------------
// Transpose + split: in is R x C fp32 row-major.
// hi[c][r] + lo[c][r] ~= in[r][c]
// float4 global loads, LDS transpose, 8B packed bf16x4 stores.
// ---------------------------------------------------------------------------
__global__ __launch_bounds__(256) void convT(
    const float* __restrict__ in, bf16* __restrict__ hi, bf16* __restrict__ lo,
    int R, int C) {
  __shared__ float tile[64][65];
  const int r0 = blockIdx.y * 64;
  const int c0 = blockIdx.x * 64;
  const int tid = threadIdx.x;
  const int lr = tid >> 4;         // 0..15
  const int lc4 = (tid & 15) * 4;  // 0..60
#pragma unroll
  for (int p = 0; p < 4; ++p) {
    const float4 v = *reinterpret_cast<const float4*>(
        &in[(size_t)(r0 + p * 16 + lr) * C + c0 + lc4]);
    *reinterpret_cast<float4*>(&tile[p * 16 + lr][lc4]) = v;
  }
  __syncthreads();
  const int oc = tid >> 4;         // col within tile (per pass +16*p)
  const int orr = (tid & 15) * 4;  // row quad
#pragma unroll
  for (int p = 0; p < 4; ++p) {
    const int cc = p * 16 + oc;
    const float v0 = tile[orr + 0][cc];
    const float v1 = tile[orr + 1][cc];
    const float v2 = tile[orr + 2][cc];
    const float v3 = tile[orr + 3][cc];
    const bf16 h0 = (bf16)v0, h1 = (bf16)v1, h2 = (bf16)v2, h3 = (bf16)v3;
    const bf16 g0 = (bf16)(v0 - (float)h0);
    const bf16 g1 = (bf16)(v1 - (float)h1);
    const bf16 g2 = (bf16)(v2 - (float)h2);
    const bf16 g3 = (bf16)(v3 - (float)h3);
    union { bf16 b[4]; uint64_t u; } H, L;
    H.b[0] = h0; H.b[1] = h1; H.b[2] = h2; H.b[3] = h3;
    L.b[0] = g0; L.b[1] = g1; L.b[2] = g2; L.b[3] = g3;
    const size_t off = (size_t)(c0 + cc) * R + (r0 + orr);
    *reinterpret_cast<uint64_t*>(&hi[off]) = H.u;
    *reinterpret_cast<uint64_t*>(&lo[off]) = L.u;
  }
}

// ---------------------------------------------------------------------------
// GEMM: A = [M][K] (W^T hi/lo), B = [N][K] (X^T hi/lo), all K-major.
// acc += Ah*Bh + Ah*Bl + Al*Bh
// ---------------------------------------------------------------------------
__device__ __forceinline__ void gload16(const bf16* g, const bf16* l) {
  __builtin_amdgcn_global_load_lds(
      (const __attribute__((address_space(1))) void*)(g),
      (__attribute__((address_space(3))) void*)(l), 16, 0, 0);
}

__global__ __launch_bounds__(512, 1) void gemm3(
    const bf16* __restrict__ Ah, const bf16* __restrict__ Al,
    const bf16* __restrict__ Bh, const bf16* __restrict__ Bl,
    float* __restrict__ C) {
  // [buf][arr][row*32 + chunk*8]; arr: 0=Ah 1=Al 2=Bh 3=Bl. 128 KiB total.
  __shared__ __align__(16) bf16 lds[2][4][BM * BK];

  const int tid = threadIdx.x;
  const int l = tid & 63;
  const int wid = tid >> 6;

  // XCD-aware bijective swizzle: grid = 512, divisible by 8.
  const int bid = blockIdx.x;
  const int cpx = gridDim.x >> 3;  // 64
  const int swz = (bid & 7) * cpx + (bid >> 3);
  const int nbn = BATCH / BN;  // 32
  const int mb = swz / nbn;
  const int nb = swz % nbn;

  // ---- staging geometry ----
  // One gload issue: 512 thr x 16B = 8KB = 128 rows of 64B (half an array).
  // LDS dest is linear (wave base + lane*16); source chunk pre-swizzled:
  // physical chunk sc holds logical chunk sc ^ ((row>>1)&3).
  const int sr = tid >> 2;                       // row within 128-row half
  const int schunk = (tid & 3) ^ ((sr >> 1) & 3);
  const size_t gA0 = (size_t)(mb * BM + sr) * IN_F + schunk * 8;
  const size_t gA1 = (size_t)(mb * BM + 128 + sr) * IN_F + schunk * 8;
  const size_t gB0 = (size_t)(nb * BN + sr) * IN_F + schunk * 8;
  const size_t gB1 = (size_t)(nb * BN + 128 + sr) * IN_F + schunk * 8;
  const int lb0 = wid * 512;         // wave-uniform LDS base, half 0
  const int lb1 = 4096 + wid * 512;  // half 1

#define STAGE(buf, kt)                                \
  do {                                                \
    gload16(Ah + gA0 + (kt), &lds[buf][0][lb0]);      \
    gload16(Ah + gA1 + (kt), &lds[buf][0][lb1]);      \
    gload16(Al + gA0 + (kt), &lds[buf][1][lb0]);      \
    gload16(Al + gA1 + (kt), &lds[buf][1][lb1]);      \
    gload16(Bh + gB0 + (kt), &lds[buf][2][lb0]);      \
    gload16(Bh + gB1 + (kt), &lds[buf][2][lb1]);      \
    gload16(Bl + gB0 + (kt), &lds[buf][3][lb0]);      \
    gload16(Bl + gB1 + (kt), &lds[buf][3][lb1]);      \
  } while (0)

  // wave -> 128x64 output sub-tile (2 M-groups x 4 N-groups)
  const int wm = (wid >> 2) * 128;
  const int wn = (wid & 3) * 64;
  const int rl = l & 15;
  const int g4 = l >> 4;

  f32x4 acc[8][4];
#pragma unroll
  for (int i = 0; i < 8; ++i)
#pragma unroll
    for (int j = 0; j < 4; ++j) acc[i][j] = (f32x4){0.f, 0.f, 0.f, 0.f};

  // fragment LDS element offsets (row*32 + swizzled-chunk*8)
#define FOFF(row) ((row) * 32 + ((g4 ^ (((row) >> 1) & 3)) * 8))

#define COMPUTE(buf)                                                          \
  do {                                                                        \
    bf16x8 bh[4], bl[4];                                                      \
    _Pragma("unroll") for (int j = 0; j < 4; ++j) {                           \
      const int rb = wn + j * 16 + rl;                                        \
      const int ob = FOFF(rb);                                                \
      bh[j] = *reinterpret_cast<const bf16x8*>(&lds[buf][2][ob]);             \
      bl[j] = *reinterpret_cast<const bf16x8*>(&lds[buf][3][ob]);             \
    }                                                                         \
    _Pragma("unroll") for (int pi = 0; pi < 4; ++pi) {                        \
      const int ra0 = wm + (2 * pi) * 16 + rl;                                \
      const int ra1 = wm + (2 * pi + 1) * 16 + rl;                            \
      const int oa0 = FOFF(ra0);                                              \
      const int oa1 = FOFF(ra1);                                              \
      const bf16x8 a0h = *reinterpret_cast<const bf16x8*>(&lds[buf][0][oa0]); \
      const bf16x8 a0l = *reinterpret_cast<const bf16x8*>(&lds[buf][1][oa0]); \
      const bf16x8 a1h = *reinterpret_cast<const bf16x8*>(&lds[buf][0][oa1]); \
      const bf16x8 a1l = *reinterpret_cast<const bf16x8*>(&lds[buf][1][oa1]); \
      __builtin_amdgcn_s_setprio(1);                                          \
      _Pragma("unroll") for (int j = 0; j < 4; ++j) {                         \
        acc[2 * pi][j] = __builtin_amdgcn_mfma_f32_16x16x32_bf16(             \
            a0h, bh[j], acc[2 * pi][j], 0, 0, 0);                             \
        acc[2 * pi][j] = __builtin_amdgcn_mfma_f32_16x16x32_bf16(             \
            a0h, bl[j], acc[2 * pi][j], 0, 0, 0);                             \
        acc[2 * pi][j] = __builtin_amdgcn_mfma_f32_16x16x32_bf16(             \
            a0l, bh[j], acc[2 * pi][j], 0, 0, 0);                             \
        acc[2 * pi + 1][j] = __builtin_amdgcn_mfma_f32_16x16x32_bf16(         \
            a1h, bh[j], acc[2 * pi + 1][j], 0, 0, 0);                         \
        acc[2 * pi + 1][j] = __builtin_amdgcn_mfma_f32_16x16x32_bf16(         \
            a1h, bl[j], acc[2 * pi + 1][j], 0, 0, 0);                         \
        acc[2 * pi + 1][j] = __builtin_amdgcn_mfma_f32_16x16x32_bf16(         \
            a1l, bh[j], acc[2 * pi + 1][j], 0, 0, 0);                         \
      }                                                                       \
      __builtin_amdgcn_s_setprio(0);                                          \
    }                                                                         \
  } while (0)

  // ---- main loop: stage next tile BEFORE computing current (issue-early);
  //      one vmcnt(0)+lgkmcnt(0)+barrier (__syncthreads) per tile flip. ----
  STAGE(0, 0);
  __syncthreads();
  int kt = 0;
#pragma unroll 1
  for (int it = 0; it < 63; ++it) {
    STAGE(1, kt + 32);
    COMPUTE(0);
    __syncthreads();
    STAGE(0, kt + 64);
    COMPUTE(1);
    __syncthreads();
    kt += 64;
  }
  // kt == 4032: last two tiles
  STAGE(1, kt + 32);
  COMPUTE(0);
  __syncthreads();
  COMPUTE(1);

  // Epilogue. 16x16x32 C/D layout: col = lane&15, row = (lane>>4)*4 + reg.
  const int m0 = mb * BM + wm + g4 * 4;
  const int n0 = nb * BN + wn + rl;
#pragma unroll
  for (int i = 0; i < 8; ++i)
#pragma unroll
    for (int j = 0; j < 4; ++j)
#pragma unroll
      for (int r = 0; r < 4; ++r)
        C[(size_t)(m0 + i * 16 + r) * BATCH + (n0 + j * 16)] = acc[i][j][r];
#undef STAGE
#undef COMPUTE
#undef FOFF
}

// ---------------------------------------------------------------------------
// Fallback (only if ws_size too small): naive fp32.
// ---------------------------------------------------------------------------
__global__ __launch_bounds__(256) void naive_kernel(
    const float* __restrict__ W, const float* __restrict__ X,
    float* __restrict__ out) {
  const int n = blockIdx.x * 64 + threadIdx.x;
  const int m = blockIdx.y * 4 + threadIdx.y;
  float s = 0.f;
  for (int k = 0; k < IN_F; ++k)
    s = fmaf(W[(size_t)k * OUT_F + m], X[(size_t)k * BATCH + n], s);
  out[(size_t)m * BATCH + n] = s;
}

extern "C" void kernel_launch(void* const* d_in, const int* in_sizes, int n_in,
                              void* d_out, int out_size, void* d_ws,
                              size_t ws_size, hipStream_t stream) {
  const float* X = (const float*)d_in[0];  // (IN_F, BATCH)
  const float* W = (const float*)d_in[1];  // (IN_F, OUT_F)
  float* out = (float*)d_out;              // (OUT_F, BATCH)

  const size_t szA = (size_t)OUT_F * IN_F;
  const size_t szB = (size_t)BATCH * IN_F;
  const size_t need = (2 * szA + 2 * szB) * sizeof(bf16);  // 192 MB

  if (d_ws == nullptr || ws_size < need) {
    naive_kernel<<<dim3(BATCH / 64, OUT_F / 4), dim3(64, 4), 0, stream>>>(W, X,
                                                                          out);
    return;
  }

  bf16* Ah = (bf16*)d_ws;
  bf16* Al = Ah + szA;
  bf16* Bh = Al + szA;
  bf16* Bl = Bh + szB;

  // W (IN_F x OUT_F) -> Ah/Al (OUT_F x IN_F)
  convT<<<dim3(OUT_F / 64, IN_F / 64), dim3(256), 0, stream>>>(W, Ah, Al, IN_F,
                                                               OUT_F);
  // X (IN_F x BATCH) -> Bh/Bl (BATCH x IN_F)
  convT<<<dim3(BATCH / 64, IN_F / 64), dim3(256), 0, stream>>>(X, Bh, Bl, IN_F,
                                                               BATCH);

  gemm3<<<dim3((OUT_F / BM) * (BATCH / BN)), dim3(512), 0, stream>>>(Ah, Al, Bh,
                                                                     Bl, out);
}

// Round 5
// 576.745 us; speedup vs baseline: 1.7389x; 1.7158x over previous
//
#include <hip/hip_runtime.h>
#include <stdint.h>

// SparseLayer = dense GEMM: C[o][b] = sum_i W[i][o] * X[i][b]
//   M = OUT_F = 4096, N = BATCH = 8192, K = IN_F = 4096, fp32 in/out.
// Round 5 (= round 4 resubmit; infra failure): single-pass fp16
// (error ~0.05 << 0.5 threshold), 256x256xBK64, 8 waves, m201-style
// 8-phase schedule with counted vmcnt(3) (T3+T4), chunk^(row&7)
// both-sides LDS swizzle (T2), setprio around MFMA (T5), XCD-aware
// block swizzle (T1). Raw s_barrier only — no vmcnt(0) drains in the
// main loop.

#define IN_F 4096
#define OUT_F 4096
#define BATCH 8192

typedef _Float16 f16;
typedef _Float16 f16x8 __attribute__((ext_vector_type(8)));
typedef float f32x4 __attribute__((ext_vector_type(4)));

// ---------------------------------------------------------------------------
// Transpose + convert: in is R x C fp32 row-major; out[c][r] = (f16)in[r][c].
// float4 global loads, LDS transpose, 8B packed f16x4 stores.
// ---------------------------------------------------------------------------
__global__ __launch_bounds__(256) void convT(const float* __restrict__ in,
                                             f16* __restrict__ out, int R,
                                             int C) {
  __shared__ float tile[64][65];
  const int r0 = blockIdx.y * 64;
  const int c0 = blockIdx.x * 64;
  const int tid = threadIdx.x;
  const int lr = tid >> 4;         // 0..15
  const int lc4 = (tid & 15) * 4;  // 0..60
#pragma unroll
  for (int p = 0; p < 4; ++p) {
    const float4 v = *reinterpret_cast<const float4*>(
        &in[(size_t)(r0 + p * 16 + lr) * C + c0 + lc4]);
    *reinterpret_cast<float4*>(&tile[p * 16 + lr][lc4]) = v;
  }
  __syncthreads();
  const int oc = tid >> 4;         // col within tile (per pass +16*p)
  const int orr = (tid & 15) * 4;  // row quad
#pragma unroll
  for (int p = 0; p < 4; ++p) {
    const int cc = p * 16 + oc;
    union { f16 h[4]; uint64_t u; } P;
    P.h[0] = (f16)tile[orr + 0][cc];
    P.h[1] = (f16)tile[orr + 1][cc];
    P.h[2] = (f16)tile[orr + 2][cc];
    P.h[3] = (f16)tile[orr + 3][cc];
    *reinterpret_cast<uint64_t*>(&out[(size_t)(c0 + cc) * R + (r0 + orr)]) =
        P.u;
  }
}

// ---------------------------------------------------------------------------
// GEMM: A = [M][K] fp16 (W^T), B = [N][K] fp16 (X^T), C = [M][N] fp32.
// 256x256 tile, BK=64, 8 waves (2M x 4N), per-wave output 128x64.
// LDS: Alds[buf][slice p][64 rows x 64 k] where slice p = A-rows
// {p*32..p*32+32} of both M-groups; Blds[buf][chunk q][64 rows x 64 k]
// where chunk q = B-rows {q*64..}. Rows are 128B = 8 x 16B chunks;
// physical chunk c holds logical chunk c ^ (row & 7) (both-sides swizzle).
// ---------------------------------------------------------------------------
__device__ __forceinline__ void gload16(const f16* g, const f16* l) {
  __builtin_amdgcn_global_load_lds(
      (const __attribute__((address_space(1))) void*)(g),
      (__attribute__((address_space(3))) void*)(l), 16, 0, 0);
}

__global__ __launch_bounds__(512, 1) void gemm8p(const f16* __restrict__ A,
                                                 const f16* __restrict__ B,
                                                 float* __restrict__ C) {
  __shared__ __align__(16) f16 Alds[2][4][4096];  // 64 KiB
  __shared__ __align__(16) f16 Blds[2][4][4096];  // 64 KiB

  const int tid = threadIdx.x;
  const int l = tid & 63;
  const int wid = tid >> 6;

  // T1: XCD-aware bijective swizzle; grid = 512 (divisible by 8).
  const int bid = blockIdx.x;
  const int cpx = gridDim.x >> 3;
  const int swz = (bid & 7) * cpx + (bid >> 3);
  const int nbn = BATCH / 256;  // 32
  const int mb = swz / nbn;
  const int nb = swz % nbn;

  // ---- staging geometry: one wave-gload = 64 lanes x 16B = 1KB = 8 rows.
  const int r = 8 * wid + (l >> 3);          // seq row within 64-row slice
  const int lchunk = (l & 7) ^ (r & 7);      // pre-swizzled source chunk
  const f16* srcA0 =
      A + (size_t)(mb * 256 + r + ((r < 32) ? 0 : 96)) * IN_F + lchunk * 8;
  const f16* srcB0 = B + (size_t)(nb * 256 + r) * IN_F + lchunk * 8;
  const int wb = wid * 512;  // wave-uniform LDS dest base (elements)

#define SA(c, p, kt) gload16(srcA0 + (size_t)(p) * 32 * IN_F + (kt), &Alds[c][p][wb])
#define SB(c, q, kt) gload16(srcB0 + (size_t)(q) * 64 * IN_F + (kt), &Blds[c][q][wb])
#define VM3 asm volatile("s_waitcnt vmcnt(3)" ::: "memory")
#define VM0 asm volatile("s_waitcnt vmcnt(0)" ::: "memory")
#define NOGATE (void)0

  // wave -> 128x64 output sub-tile
  const int g = wid >> 2;       // M-group
  const int wq = wid & 3;       // N-group == B LDS chunk index
  const int rl = l & 15;
  const int hi = l >> 4;
  const int cx[2] = {((0 * 4 + hi) ^ (rl & 7)) * 8,
                     ((1 * 4 + hi) ^ (rl & 7)) * 8};

  f32x4 acc[8][4];
#pragma unroll
  for (int i = 0; i < 8; ++i)
#pragma unroll
    for (int j = 0; j < 4; ++j) acc[i][j] = (f32x4){0.f, 0.f, 0.f, 0.f};

  // Phase: {12 ds_read_b128; stage gloads; barrier; lgkmcnt(0); setprio(1);
  //         16 MFMA (M-slice p x 4 N x 2 kk); setprio(0); gate; barrier}.
#define PHASE(c, p, POSTGATE, ...)                                            \
  do {                                                                        \
    f16x8 af[2][2], bv[4][2];                                                 \
    _Pragma("unroll") for (int f = 0; f < 2; ++f)                             \
        _Pragma("unroll") for (int kk = 0; kk < 2; ++kk)                      \
            af[f][kk] = *reinterpret_cast<const f16x8*>(                      \
                &Alds[c][p][(32 * g + f * 16 + rl) * 64 + cx[kk]]);           \
    _Pragma("unroll") for (int n = 0; n < 4; ++n)                             \
        _Pragma("unroll") for (int kk = 0; kk < 2; ++kk)                      \
            bv[n][kk] = *reinterpret_cast<const f16x8*>(                      \
                &Blds[c][wq][(n * 16 + rl) * 64 + cx[kk]]);                   \
    __VA_ARGS__;                                                              \
    __builtin_amdgcn_s_barrier();                                             \
    asm volatile("s_waitcnt lgkmcnt(0)" ::: "memory");                        \
    __builtin_amdgcn_sched_barrier(0);                                        \
    __builtin_amdgcn_s_setprio(1);                                            \
    _Pragma("unroll") for (int n = 0; n < 4; ++n)                             \
        _Pragma("unroll") for (int f = 0; f < 2; ++f)                         \
            _Pragma("unroll") for (int kk = 0; kk < 2; ++kk)                  \
                acc[2 * (p) + f][n] = __builtin_amdgcn_mfma_f32_16x16x32_f16( \
                    af[f][kk], bv[n][kk], acc[2 * (p) + f][n], 0, 0, 0);      \
    __builtin_amdgcn_s_setprio(0);                                            \
    POSTGATE;                                                                 \
    __builtin_amdgcn_s_barrier();                                             \
  } while (0)

  // ---- prologue: tile0 (8 loads) + tile1 A-slices 0..2; gate; barrier ----
  SA(0, 0, 0); SA(0, 1, 0); SA(0, 2, 0); SA(0, 3, 0);
  SB(0, 0, 0); SB(0, 1, 0); SB(0, 2, 0); SB(0, 3, 0);
  SA(1, 0, 64); SA(1, 1, 64); SA(1, 2, 64);
  VM3;
  __builtin_amdgcn_s_barrier();

  // ---- main loop: iteration = 2 K-tiles (t=2i buf0, t+1 buf1).
  // Stage schedule (derived; vmcnt(3) = 3 loads issued after each tile's
  // last load, so the wait never drains the pipeline):
#pragma unroll 1
  for (int it = 0; it < 31; ++it) {
    const int kt = it * 128;
    PHASE(0, 0, NOGATE, SA(1, 3, kt + 64); SB(1, 0, kt + 64));
    PHASE(0, 1, NOGATE, SB(1, 1, kt + 64); SB(1, 2, kt + 64));
    PHASE(0, 2, NOGATE, SB(1, 3, kt + 64); SA(0, 0, kt + 128));
    PHASE(0, 3, VM3,    SA(0, 1, kt + 128); SA(0, 2, kt + 128));
    PHASE(1, 0, NOGATE, SA(0, 3, kt + 128); SB(0, 0, kt + 128));
    PHASE(1, 1, NOGATE, SB(0, 1, kt + 128); SB(0, 2, kt + 128));
    PHASE(1, 2, NOGATE, SB(0, 3, kt + 128); SA(1, 0, kt + 192));
    PHASE(1, 3, VM3,    SA(1, 1, kt + 192); SA(1, 2, kt + 192));
  }
  // ---- peeled last iteration (tiles 62, 63): no staging past K ----
  {
    const int kt = 31 * 128;
    PHASE(0, 0, NOGATE, SA(1, 3, kt + 64); SB(1, 0, kt + 64));
    PHASE(0, 1, NOGATE, SB(1, 1, kt + 64); SB(1, 2, kt + 64));
    PHASE(0, 2, NOGATE, SB(1, 3, kt + 64));
    PHASE(0, 3, VM0, NOGATE);
    PHASE(1, 0, NOGATE, NOGATE);
    PHASE(1, 1, NOGATE, NOGATE);
    PHASE(1, 2, NOGATE, NOGATE);
    PHASE(1, 3, NOGATE, NOGATE);
  }

  // Epilogue. 16x16 C/D layout: col = lane&15, row = (lane>>4)*4 + reg.
  const int m0 = mb * 256 + g * 128 + hi * 4;
  const int n0 = nb * 256 + wq * 64 + rl;
#pragma unroll
  for (int i = 0; i < 8; ++i)
#pragma unroll
    for (int j = 0; j < 4; ++j)
#pragma unroll
      for (int rr = 0; rr < 4; ++rr)
        C[(size_t)(m0 + i * 16 + rr) * BATCH + (n0 + j * 16)] = acc[i][j][rr];
#undef PHASE
#undef SA
#undef SB
#undef VM3
#undef VM0
#undef NOGATE
}

// ---------------------------------------------------------------------------
// Fallback (only if ws_size too small): naive fp32.
// ---------------------------------------------------------------------------
__global__ __launch_bounds__(256) void naive_kernel(
    const float* __restrict__ W, const float* __restrict__ X,
    float* __restrict__ out) {
  const int n = blockIdx.x * 64 + threadIdx.x;
  const int m = blockIdx.y * 4 + threadIdx.y;
  float s = 0.f;
  for (int k = 0; k < IN_F; ++k)
    s = fmaf(W[(size_t)k * OUT_F + m], X[(size_t)k * BATCH + n], s);
  out[(size_t)m * BATCH + n] = s;
}

extern "C" void kernel_launch(void* const* d_in, const int* in_sizes, int n_in,
                              void* d_out, int out_size, void* d_ws,
                              size_t ws_size, hipStream_t stream) {
  const float* X = (const float*)d_in[0];  // (IN_F, BATCH)
  const float* W = (const float*)d_in[1];  // (IN_F, OUT_F)
  float* out = (float*)d_out;              // (OUT_F, BATCH)

  const size_t szA = (size_t)OUT_F * IN_F;
  const size_t szB = (size_t)BATCH * IN_F;
  const size_t need = (szA + szB) * sizeof(f16);  // 96 MB

  if (d_ws == nullptr || ws_size < need) {
    naive_kernel<<<dim3(BATCH / 64, OUT_F / 4), dim3(64, 4), 0, stream>>>(W, X,
                                                                          out);
    return;
  }

  f16* Ah = (f16*)d_ws;
  f16* Bh = Ah + szA;

  // W (IN_F x OUT_F) -> A (OUT_F x IN_F)
  convT<<<dim3(OUT_F / 64, IN_F / 64), dim3(256), 0, stream>>>(W, Ah, IN_F,
                                                               OUT_F);
  // X (IN_F x BATCH) -> B (BATCH x IN_F)
  convT<<<dim3(BATCH / 64, IN_F / 64), dim3(256), 0, stream>>>(X, Bh, IN_F,
                                                               BATCH);

  gemm8p<<<dim3((OUT_F / 256) * (BATCH / 256)), dim3(512), 0, stream>>>(Ah, Bh,
                                                                        out);
}